// Round 8
// baseline (623.213 us; speedup 1.0000x reference)
//
#include <hip/hip_runtime.h>
#include <stdint.h>

// Problem dims (fixed)
constexpr int T_DIM   = 16384;
constexpr int IN_DIM  = 4096;
constexpr int OUT_DIM = 4096;

using int32x4 = __attribute__((ext_vector_type(4))) int;

#define GLOAD_LDS16(g, l)                                                     \
    __builtin_amdgcn_global_load_lds(                                         \
        (const __attribute__((address_space(1))) void*)(uintptr_t)(g),        \
        (__attribute__((address_space(3))) void*)(uintptr_t)(l), 16, 0, 0)

// ===========================================================================
// Pre-pass: int32 (int8-valued) -> packed int8, pre-swizzled: within each
// 64-B group of 4 chunks, stored = chunk ^ ((row>>1)&3).  (rule #21)
// ===========================================================================
__global__ void pack_swz(const int* __restrict__ src, int8_t* __restrict__ dst,
                         int rows, int cols) {
    int64_t tid = (int64_t)blockIdx.x * blockDim.x + threadIdx.x;
    int64_t nchunks = (int64_t)rows * (cols / 16);
    if (tid >= nchunks) return;
    int row  = (int)(tid / (cols / 16));
    int cidx = (int)(tid % (cols / 16));
    const int32x4* s4 =
        reinterpret_cast<const int32x4*>(src + (int64_t)row * cols + (cidx << 4));
    uint32_t p[4];
#pragma unroll
    for (int v = 0; v < 4; ++v) {
        int32x4 t = s4[v];
        p[v] = (uint32_t)(t[0] & 0xff) | ((uint32_t)(t[1] & 0xff) << 8) |
               ((uint32_t)(t[2] & 0xff) << 16) | ((uint32_t)(t[3] & 0xff) << 24);
    }
    int cs = (cidx & ~3) | ((cidx & 3) ^ ((row >> 1) & 3));
    *reinterpret_cast<int32x4*>(dst + (int64_t)row * cols + (cs << 4)) =
        *reinterpret_cast<int32x4*>(p);
}

// ===========================================================================
// Main GEMM: 256x256 tile, BK=64 int8, 8 waves (2Mx4N), per-wave 128x64.
// 4-buffer LDS pipeline (128 KiB), counted vmcnt(4).
// ROUND 8: ASYMMETRIC register prefetch (fits the 128 arch-VGPR half of the
// 256-reg budget; R7's full A+B ping-pong spilled):
//   - A fragments double-buffered (64 regs): tile t body reads A(t+1) from
//     buf((t+1)&3) AFTER issuing B(t) reads; lgkm retires DS in order, so
//     the compiler's wait before the first MFMA (needs bf[0]) drains only
//     the 4 B reads and leaves all 8 A(t+1) reads in flight UNDER the MFMA
//     burst (2/3 of LDS read traffic hidden).
//   - B fragments single-buffered (16 regs), read fresh each tile.
//   - asm("":::"memory") between B and A reads pins the DS issue order.
// Boundary (= R7, proven): stage(t+3)->buf((t+3)&3); vmcnt(4) ensures
// buf(t+2) landed block-wide (per-wave vmcnt + s_barrier); WAR on
// stage->buf(t-1) safe (its readers drained a full barrier earlier).
// ===========================================================================
constexpr int BM = 256, BN = 256, BK = 64;
constexpr int NT    = IN_DIM / BK;     // 64
constexpr int ATILE = BM * BK;         // 16 KiB
constexpr int BUFSZ = 2 * ATILE;       // 32 KiB (A + B)

__global__ __launch_bounds__(512, 2)
void gemm_i8_8p(const int8_t* __restrict__ x8, const int8_t* __restrict__ w8,
                const int* __restrict__ bias, const float* __restrict__ alphap,
                const float* __restrict__ betap, int* __restrict__ out) {
    __shared__ __align__(16) int8_t lds[4 * BUFSZ];   // 128 KiB

    const int tid  = threadIdx.x;
    const int lane = tid & 63;
    const int wid  = tid >> 6;
    const int wr   = wid >> 2;   // 0..1
    const int wc   = wid & 3;    // 0..3

    // XCD-chunked bijective swizzle (nwg = 1024, %8==0)
    const int nwg = gridDim.x;
    const int cpx = nwg >> 3;
    const int bid = blockIdx.x;
    const int swz = (bid & 7) * cpx + (bid >> 3);
    const int bm  = swz >> 4;    // 64 M-blocks
    const int bn  = swz & 15;    // 16 N-blocks
    const int brow = bm * BM;
    const int bcol = bn * BN;

    const float alpha = *alphap;
    const float beta  = *betap;

    const int g = lane >> 4;     // K-chunk 0..3 (16 int8 each)
    const int r = lane & 15;

    // ---- hoisted staging addresses: 4 moving global pointers (+BK/tile)
    const int offL0 = tid * 16;            // half 0: rows 0..127
    const int offL1 = 8192 + tid * 16;     // half 1: rows 128..255
    const int rowL0 = offL0 >> 6, inL0 = offL0 & 63;
    const int rowL1 = offL1 >> 6, inL1 = offL1 & 63;
    const int8_t* pA0 = x8 + (int64_t)(brow + rowL0) * IN_DIM + inL0;
    const int8_t* pA1 = x8 + (int64_t)(brow + rowL1) * IN_DIM + inL1;
    const int8_t* pB0 = w8 + (int64_t)(bcol + rowL0) * IN_DIM + inL0;
    const int8_t* pB1 = w8 + (int64_t)(bcol + rowL1) * IN_DIM + inL1;
    const int dA0 = offL0, dA1 = offL1;
    const int dB0 = ATILE + offL0, dB1 = ATILE + offL1;

    // ---- hoisted fragment byte-offsets (buffer-invariant; swizzle baked in)
    int aoff[8], boff[4];
#pragma unroll
    for (int m = 0; m < 8; ++m) {
        const int row = wr * 128 + m * 16 + r;
        aoff[m] = row * BK + ((g ^ ((row >> 1) & 3)) << 4);
    }
#pragma unroll
    for (int n = 0; n < 4; ++n) {
        const int row = wc * 64 + n * 16 + r;
        boff[n] = ATILE + row * BK + ((g ^ ((row >> 1) & 3)) << 4);
    }

    int32x4 acc[8][4] = {};
    int32x4 fA0[8], fA1[8];   // A fragment ping-pong (the only reg dbuf)

#define STAGE4(BIDX)                                                          \
    do {                                                                      \
        int8_t* nb = lds + (BIDX) * BUFSZ;                                    \
        GLOAD_LDS16(pA0, nb + dA0);  GLOAD_LDS16(pA1, nb + dA1);              \
        GLOAD_LDS16(pB0, nb + dB0);  GLOAD_LDS16(pB1, nb + dB1);              \
        pA0 += BK; pA1 += BK; pB0 += BK; pB1 += BK;                           \
    } while (0)

    // Tile body. CURB = t&3 (B source), NXTB = (t+1)&3 (A-next source),
    // STGB = (t+3)&3. FAC = A frags for THIS tile, FAN = set to fill.
    // VM: 4 = steady, 0 = drain, -1 = barrier only.
#define TILE(CURB, NXTB, STGB, FAC, FAN, PF, VM)                              \
    do {                                                                      \
        if (PF) STAGE4(STGB);                                                 \
        const int8_t* cb = lds + (CURB) * BUFSZ;                              \
        const int8_t* nb = lds + (NXTB) * BUFSZ;                              \
        int32x4 bf[4];                                                        \
        _Pragma("unroll") for (int n = 0; n < 4; ++n)                         \
            bf[n] = *reinterpret_cast<const int32x4*>(cb + boff[n]);          \
        asm volatile("" ::: "memory"); /* pin DS order: B(t) before A(t+1) */ \
        _Pragma("unroll") for (int m = 0; m < 8; ++m)                         \
            FAN[m] = *reinterpret_cast<const int32x4*>(nb + aoff[m]);         \
        __builtin_amdgcn_s_setprio(1);                                        \
        _Pragma("unroll") for (int m = 0; m < 8; ++m)                         \
            _Pragma("unroll") for (int n = 0; n < 4; ++n)                     \
                acc[m][n] = __builtin_amdgcn_mfma_i32_16x16x64_i8(            \
                    FAC[m], bf[n], acc[m][n], 0, 0, 0);                       \
        __builtin_amdgcn_s_setprio(0);                                        \
        if ((VM) == 4)      asm volatile("s_waitcnt vmcnt(4)" ::: "memory");  \
        else if ((VM) == 0) asm volatile("s_waitcnt vmcnt(0)" ::: "memory");  \
        __builtin_amdgcn_s_barrier();                                         \
        asm volatile("" ::: "memory");                                        \
    } while (0)

    // Prologue: stage tiles 0,1,2; wait until buf0 AND buf1 landed (tile-0
    // body reads B(0) from buf0 and A(1) from buf1); pre-read A(0) -> fA0.
    STAGE4(0); STAGE4(1); STAGE4(2);
    asm volatile("s_waitcnt vmcnt(4)" ::: "memory");
    __builtin_amdgcn_s_barrier();
    asm volatile("" ::: "memory");
#pragma unroll
    for (int m = 0; m < 8; ++m)
        fA0[m] = *reinterpret_cast<const int32x4*>(lds + aoff[m]);

    // Main loop: tiles 0..59, 4-tile unroll, all indices literal.
    // Tile t: FAC = fA[t&1], FAN = fA[(t+1)&1].
#pragma unroll 1
    for (int tt = 0; tt < NT - 4; tt += 4) {
        TILE(0, 1, 3, fA0, fA1, true, 4);
        TILE(1, 2, 0, fA1, fA0, true, 4);
        TILE(2, 3, 1, fA0, fA1, true, 4);
        TILE(3, 0, 2, fA1, fA0, true, 4);
    }
    // Tail: tiles 60..63. Stage 63 during 60; drain vmcnt 4 -> 0.
    TILE(0, 1, 3, fA0, fA1, true,  4);   // t=60
    TILE(1, 2, 0, fA1, fA0, false, 0);   // t=61 (vmcnt(0): buf3=tile63 lands)
    TILE(2, 3, 0, fA0, fA1, false, -1);  // t=62 (reads A(63) from buf3)
    {   // t=63: B(63) from buf3 + MFMA on fA1; no prefetch, no boundary.
        const int8_t* cb = lds + 3 * BUFSZ;
        int32x4 bf[4];
#pragma unroll
        for (int n = 0; n < 4; ++n)
            bf[n] = *reinterpret_cast<const int32x4*>(cb + boff[n]);
        __builtin_amdgcn_s_setprio(1);
#pragma unroll
        for (int m = 0; m < 8; ++m)
#pragma unroll
            for (int n = 0; n < 4; ++n)
                acc[m][n] = __builtin_amdgcn_mfma_i32_16x16x64_i8(
                    fA1[m], bf[n], acc[m][n], 0, 0, 0);
        __builtin_amdgcn_s_setprio(0);
    }
#undef TILE
#undef STAGE4

    // Epilogue: y = acc*alpha + bias*beta, round, clip, store int32.
    // C/D: col = lane&15, row = (lane>>4)*4 + j.
    const int r4 = (lane >> 4) * 4;
    const int cl = lane & 15;
#pragma unroll
    for (int n = 0; n < 4; ++n) {
        const int col = bcol + wc * 64 + n * 16 + cl;
        const float bterm = (float)bias[col] * beta;
#pragma unroll
        for (int m = 0; m < 8; ++m) {
            const int row0 = brow + wr * 128 + m * 16 + r4;
#pragma unroll
            for (int j = 0; j < 4; ++j) {
                float y = (float)acc[m][n][j] * alpha + bterm;
                y = rintf(y);
                y = fminf(fmaxf(y, -128.0f), 127.0f);
                out[(int64_t)(row0 + j) * OUT_DIM + col] = (int)y;
            }
        }
    }
}

// ===========================================================================
// Fallback (ws too small): reads int32 inputs directly, packs in regs,
// swizzled ds_write. 128x128 tile. Known-correct (round 2).
// ===========================================================================
__global__ __launch_bounds__(256)
void gemm_i8_fb(const int* __restrict__ x32, const int* __restrict__ w32,
                const int* __restrict__ bias, const float* __restrict__ alphap,
                const float* __restrict__ betap, int* __restrict__ out) {
    constexpr int FBM = 128, FBK = 128;
    __shared__ int8_t lA[FBM * FBK];
    __shared__ int8_t lB[FBM * FBK];

    const int tid  = threadIdx.x;
    const int wid  = tid >> 6;
    const int lane = tid & 63;
    const int nwg = gridDim.x;
    const int cpx = nwg >> 3;
    const int bid = blockIdx.x;
    const int swz = (bid & 7) * cpx + (bid >> 3);
    const int brow = (swz >> 5) * FBM;
    const int bcol = (swz & 31) * FBM;
    const int wr = wid >> 1, wc = wid & 1;
    const float alpha = *alphap;
    const float beta  = *betap;

    int32x4 acc[4][4] = {};
    for (int kt = 0; kt < IN_DIM / FBK; ++kt) {
        const int64_t kbase = (int64_t)kt * FBK;
#pragma unroll
        for (int q = 0; q < 4; ++q) {
            const int off = wid * 4096 + q * 1024 + lane * 16;
            const int row = off >> 7;
            const int k   = off & 127;
            const int* ga = x32 + (int64_t)(brow + row) * IN_DIM + kbase + k;
            const int* gb = w32 + (int64_t)(bcol + row) * IN_DIM + kbase + k;
            uint32_t pa[4], pb[4];
#pragma unroll
            for (int v = 0; v < 4; ++v) {
                int32x4 ta = reinterpret_cast<const int32x4*>(ga)[v];
                int32x4 tb = reinterpret_cast<const int32x4*>(gb)[v];
                pa[v] = (uint32_t)(ta[0] & 0xff) | ((uint32_t)(ta[1] & 0xff) << 8) |
                        ((uint32_t)(ta[2] & 0xff) << 16) | ((uint32_t)(ta[3] & 0xff) << 24);
                pb[v] = (uint32_t)(tb[0] & 0xff) | ((uint32_t)(tb[1] & 0xff) << 8) |
                        ((uint32_t)(tb[2] & 0xff) << 16) | ((uint32_t)(tb[3] & 0xff) << 24);
            }
            const int sc = ((k >> 4) ^ (row & 7)) << 4;
            *reinterpret_cast<int32x4*>(lA + row * FBK + sc) = *reinterpret_cast<int32x4*>(pa);
            *reinterpret_cast<int32x4*>(lB + row * FBK + sc) = *reinterpret_cast<int32x4*>(pb);
        }
        __syncthreads();
#pragma unroll
        for (int ks = 0; ks < 2; ++ks) {
            const int gg = lane >> 4, rr = lane & 15;
            const int lc = ks * 4 + gg;
            int32x4 af[4], bf[4];
#pragma unroll
            for (int m = 0; m < 4; ++m) {
                const int row = wr * 64 + m * 16 + rr;
                af[m] = *reinterpret_cast<const int32x4*>(lA + row * FBK + ((lc ^ (row & 7)) << 4));
            }
#pragma unroll
            for (int n = 0; n < 4; ++n) {
                const int row = wc * 64 + n * 16 + rr;
                bf[n] = *reinterpret_cast<const int32x4*>(lB + row * FBK + ((lc ^ (row & 7)) << 4));
            }
#pragma unroll
            for (int m = 0; m < 4; ++m)
#pragma unroll
                for (int n = 0; n < 4; ++n)
                    acc[m][n] = __builtin_amdgcn_mfma_i32_16x16x64_i8(af[m], bf[n], acc[m][n], 0, 0, 0);
        }
        __syncthreads();
    }
    const int r4 = (lane >> 4) * 4;
    const int cl = lane & 15;
#pragma unroll
    for (int n = 0; n < 4; ++n) {
        const int col = bcol + wc * 64 + n * 16 + cl;
        const float bterm = (float)bias[col] * beta;
#pragma unroll
        for (int m = 0; m < 4; ++m) {
            const int row0 = brow + wr * 64 + m * 16 + r4;
#pragma unroll
            for (int j = 0; j < 4; ++j) {
                float y = (float)acc[m][n][j] * alpha + bterm;
                y = rintf(y);
                y = fminf(fmaxf(y, -128.0f), 127.0f);
                out[(int64_t)(row0 + j) * OUT_DIM + col] = (int)y;
            }
        }
    }
}

// ===========================================================================
extern "C" void kernel_launch(void* const* d_in, const int* in_sizes, int n_in,
                              void* d_out, int out_size, void* d_ws, size_t ws_size,
                              hipStream_t stream) {
    const int*   x     = (const int*)d_in[0];
    const int*   w     = (const int*)d_in[1];
    const int*   bias  = (const int*)d_in[2];
    const float* alpha = (const float*)d_in[3];
    const float* beta  = (const float*)d_in[4];
    int*         out   = (int*)d_out;

    const size_t need = (size_t)T_DIM * IN_DIM + (size_t)OUT_DIM * IN_DIM;

    if (ws_size >= need) {
        int8_t* x8 = (int8_t*)d_ws;
        int8_t* w8 = x8 + (size_t)T_DIM * IN_DIM;
        {
            int64_t nch = (int64_t)T_DIM * (IN_DIM / 16);
            pack_swz<<<(int)((nch + 255) / 256), 256, 0, stream>>>(x, x8, T_DIM, IN_DIM);
        }
        {
            int64_t nch = (int64_t)OUT_DIM * (IN_DIM / 16);
            pack_swz<<<(int)((nch + 255) / 256), 256, 0, stream>>>(w, w8, OUT_DIM, IN_DIM);
        }
        const int grid = (T_DIM / BM) * (OUT_DIM / BN);  // 1024
        gemm_i8_8p<<<grid, 512, 0, stream>>>(x8, w8, bias, alpha, beta, out);
    } else {
        const int grid = (T_DIM / 128) * (OUT_DIM / 128);  // 4096
        gemm_i8_fb<<<grid, 256, 0, stream>>>(x, w, bias, alpha, beta, out);
    }
}

// Round 9
// 383.224 us; speedup vs baseline: 1.6262x; 1.6262x over previous
//
#include <hip/hip_runtime.h>
#include <stdint.h>

// Problem dims (fixed)
constexpr int T_DIM   = 16384;
constexpr int IN_DIM  = 4096;
constexpr int OUT_DIM = 4096;

using int32x4 = __attribute__((ext_vector_type(4))) int;

#define GLOAD_LDS16(g, l)                                                     \
    __builtin_amdgcn_global_load_lds(                                         \
        (const __attribute__((address_space(1))) void*)(uintptr_t)(g),        \
        (__attribute__((address_space(3))) void*)(uintptr_t)(l), 16, 0, 0)

// ===========================================================================
// Pre-pass: int32 (int8-valued) -> packed int8, pre-swizzled for BK=128:
// within each 128-B group of 8 chunks, stored = chunk ^ (row & 7). (rule #21)
// ===========================================================================
__global__ void pack_swz(const int* __restrict__ src, int8_t* __restrict__ dst,
                         int rows, int cols) {
    int64_t tid = (int64_t)blockIdx.x * blockDim.x + threadIdx.x;
    int64_t nchunks = (int64_t)rows * (cols / 16);
    if (tid >= nchunks) return;
    int row  = (int)(tid / (cols / 16));
    int cidx = (int)(tid % (cols / 16));
    const int32x4* s4 =
        reinterpret_cast<const int32x4*>(src + (int64_t)row * cols + (cidx << 4));
    uint32_t p[4];
#pragma unroll
    for (int v = 0; v < 4; ++v) {
        int32x4 t = s4[v];
        p[v] = (uint32_t)(t[0] & 0xff) | ((uint32_t)(t[1] & 0xff) << 8) |
               ((uint32_t)(t[2] & 0xff) << 16) | ((uint32_t)(t[3] & 0xff) << 24);
    }
    int cs = (cidx & ~7) | ((cidx & 7) ^ (row & 7));
    *reinterpret_cast<int32x4*>(dst + (int64_t)row * cols + (cs << 4)) =
        *reinterpret_cast<int32x4*>(p);
}

// ===========================================================================
// Main GEMM: 256x256 tile, BK=128 int8 (ROUND 9: doubled K-tile to amortize
// the measured ~2700cy fixed per-tile overhead over 2x the MFMA work; m201
// cross-check: bf16 template runs the same ~3300cy/tile wall with 2x MFMA).
// 2 LDS buffers of 64 KiB (A 32K + B 32K) = 128 KiB. 8 waves (2Mx4N),
// per-wave 128x64 output, acc[8][4] (128 AGPRs).
// Per tile: stage 8 gloads (tile t+1 -> other buffer), 2 ks-phases of
// {12 ds_read_b128 + 32 MFMA}, then vmcnt(0)+barrier boundary.
// No reg double-buffering (R7/R8 proved it spills the 256-reg/wave budget).
// WAR safety: buf (t+1)&1's readers finished at the end-of-(t-1) barrier.
// Swizzle: chunk' = chunk ^ (row&7) in 8-chunk groups; phase-1 read offsets
// are phase-0 offsets ^ 64 (chunk +4 = XOR bit2, no carry into row bits).
// ===========================================================================
constexpr int BM = 256, BN = 256, BK = 128;
constexpr int NT    = IN_DIM / BK;     // 32
constexpr int ATILE = BM * BK;         // 32 KiB
constexpr int BUFSZ = 2 * ATILE;       // 64 KiB (A + B)

__global__ __launch_bounds__(512, 2)
void gemm_i8_8p(const int8_t* __restrict__ x8, const int8_t* __restrict__ w8,
                const int* __restrict__ bias, const float* __restrict__ alphap,
                const float* __restrict__ betap, int* __restrict__ out) {
    __shared__ __align__(16) int8_t lds[2 * BUFSZ];   // 128 KiB

    const int tid  = threadIdx.x;
    const int lane = tid & 63;
    const int wid  = tid >> 6;
    const int wr   = wid >> 2;   // 0..1
    const int wc   = wid & 3;    // 0..3

    // XCD-chunked bijective swizzle (nwg = 1024, %8==0)
    const int nwg = gridDim.x;
    const int cpx = nwg >> 3;
    const int bid = blockIdx.x;
    const int swz = (bid & 7) * cpx + (bid >> 3);
    const int bm  = swz >> 4;    // 64 M-blocks
    const int bn  = swz & 15;    // 16 N-blocks
    const int brow = bm * BM;
    const int bcol = bn * BN;

    const float alpha = *alphap;
    const float beta  = *betap;

    const int g = lane >> 4;     // 16B chunk within 64B K-step (0..3)
    const int r = lane & 15;

    // ---- staging: 8 moving global pointers (+BK per tile), 8 LDS dests.
    // load l (0..3) of A covers bytes [l*8192, l*8192+8192): row = off>>7.
    const int8_t* pA[4];
    const int8_t* pB[4];
    int dA[4], dB[4];
#pragma unroll
    for (int l = 0; l < 4; ++l) {
        const int off = l * 8192 + tid * 16;
        const int row = off >> 7, in = off & 127;
        pA[l] = x8 + (int64_t)(brow + row) * IN_DIM + in;
        pB[l] = w8 + (int64_t)(bcol + row) * IN_DIM + in;
        dA[l] = off;
        dB[l] = ATILE + off;
    }

    // ---- fragment byte-offsets for ks=0 (ks=1 = ^64), swizzle baked in
    int aoff[8], boff[4];
#pragma unroll
    for (int m = 0; m < 8; ++m) {
        const int row = wr * 128 + m * 16 + r;
        aoff[m] = row * BK + ((g ^ (row & 7)) << 4);
    }
#pragma unroll
    for (int n = 0; n < 4; ++n) {
        const int row = wc * 64 + n * 16 + r;
        boff[n] = ATILE + row * BK + ((g ^ (row & 7)) << 4);
    }

    int32x4 acc[8][4] = {};

#define STAGE8(DSTB)                                                          \
    do {                                                                      \
        int8_t* nb = lds + (DSTB) * BUFSZ;                                    \
        _Pragma("unroll") for (int l = 0; l < 4; ++l) {                       \
            GLOAD_LDS16(pA[l], nb + dA[l]);                                   \
            GLOAD_LDS16(pB[l], nb + dB[l]);                                   \
            pA[l] += BK; pB[l] += BK;                                         \
        }                                                                     \
    } while (0)

    // Tile body: stage t+1, two ks-phases {12 reads + 32 MFMA}, boundary.
#define TILE(RB, SB, PF, LAST)                                                \
    do {                                                                      \
        const int8_t* rb = lds + (RB) * BUFSZ;                                \
        if (PF) STAGE8(SB);                                                   \
        int32x4 af[8], bf[4];                                                 \
        /* ks = 0 */                                                          \
        _Pragma("unroll") for (int n = 0; n < 4; ++n)                         \
            bf[n] = *reinterpret_cast<const int32x4*>(rb + boff[n]);          \
        _Pragma("unroll") for (int m = 0; m < 8; ++m)                         \
            af[m] = *reinterpret_cast<const int32x4*>(rb + aoff[m]);          \
        __builtin_amdgcn_s_setprio(1);                                        \
        _Pragma("unroll") for (int m = 0; m < 8; ++m)                         \
            _Pragma("unroll") for (int n = 0; n < 4; ++n)                     \
                acc[m][n] = __builtin_amdgcn_mfma_i32_16x16x64_i8(            \
                    af[m], bf[n], acc[m][n], 0, 0, 0);                        \
        __builtin_amdgcn_s_setprio(0);                                        \
        /* ks = 1: offsets ^64 */                                             \
        _Pragma("unroll") for (int n = 0; n < 4; ++n)                         \
            bf[n] = *reinterpret_cast<const int32x4*>(rb + (boff[n] ^ 64));   \
        _Pragma("unroll") for (int m = 0; m < 8; ++m)                         \
            af[m] = *reinterpret_cast<const int32x4*>(rb + (aoff[m] ^ 64));   \
        __builtin_amdgcn_s_setprio(1);                                        \
        _Pragma("unroll") for (int m = 0; m < 8; ++m)                         \
            _Pragma("unroll") for (int n = 0; n < 4; ++n)                     \
                acc[m][n] = __builtin_amdgcn_mfma_i32_16x16x64_i8(            \
                    af[m], bf[n], acc[m][n], 0, 0, 0);                        \
        __builtin_amdgcn_s_setprio(0);                                        \
        if (!(LAST)) {                                                        \
            asm volatile("s_waitcnt vmcnt(0)" ::: "memory");                  \
            __builtin_amdgcn_s_barrier();                                     \
            asm volatile("" ::: "memory");                                    \
        }                                                                     \
    } while (0)

    // Prologue: stage tile 0 -> buf0, drain, publish.
    STAGE8(0);
    asm volatile("s_waitcnt vmcnt(0)" ::: "memory");
    __builtin_amdgcn_s_barrier();
    asm volatile("" ::: "memory");

    // Main loop: tiles 0..29 (15 iters x 2 tiles, literal buffer indices).
#pragma unroll 1
    for (int tt = 0; tt < NT - 2; tt += 2) {
        TILE(0, 1, true, false);
        TILE(1, 0, true, false);
    }
    TILE(0, 1, true,  false);   // t = 30, stages tile 31 -> buf1
    TILE(1, 0, false, true);    // t = 31, no stage, no boundary
#undef TILE
#undef STAGE8

    // Epilogue: y = acc*alpha + bias*beta, round, clip, store int32.
    // C/D: col = lane&15, row = (lane>>4)*4 + j.
    const int r4 = (lane >> 4) * 4;
    const int cl = lane & 15;
#pragma unroll
    for (int n = 0; n < 4; ++n) {
        const int col = bcol + wc * 64 + n * 16 + cl;
        const float bterm = (float)bias[col] * beta;
#pragma unroll
        for (int m = 0; m < 8; ++m) {
            const int row0 = brow + wr * 128 + m * 16 + r4;
#pragma unroll
            for (int j = 0; j < 4; ++j) {
                float y = (float)acc[m][n][j] * alpha + bterm;
                y = rintf(y);
                y = fminf(fmaxf(y, -128.0f), 127.0f);
                out[(int64_t)(row0 + j) * OUT_DIM + col] = (int)y;
            }
        }
    }
}

// ===========================================================================
// Fallback (ws too small): reads int32 inputs directly, packs in regs,
// swizzled ds_write. 128x128 tile. Known-correct (round 2). Self-contained
// swizzle (independent of the pre-pass layout).
// ===========================================================================
__global__ __launch_bounds__(256)
void gemm_i8_fb(const int* __restrict__ x32, const int* __restrict__ w32,
                const int* __restrict__ bias, const float* __restrict__ alphap,
                const float* __restrict__ betap, int* __restrict__ out) {
    constexpr int FBM = 128, FBK = 128;
    __shared__ int8_t lA[FBM * FBK];
    __shared__ int8_t lB[FBM * FBK];

    const int tid  = threadIdx.x;
    const int wid  = tid >> 6;
    const int lane = tid & 63;
    const int nwg = gridDim.x;
    const int cpx = nwg >> 3;
    const int bid = blockIdx.x;
    const int swz = (bid & 7) * cpx + (bid >> 3);
    const int brow = (swz >> 5) * FBM;
    const int bcol = (swz & 31) * FBM;
    const int wr = wid >> 1, wc = wid & 1;
    const float alpha = *alphap;
    const float beta  = *betap;

    int32x4 acc[4][4] = {};
    for (int kt = 0; kt < IN_DIM / FBK; ++kt) {
        const int64_t kbase = (int64_t)kt * FBK;
#pragma unroll
        for (int q = 0; q < 4; ++q) {
            const int off = wid * 4096 + q * 1024 + lane * 16;
            const int row = off >> 7;
            const int k   = off & 127;
            const int* ga = x32 + (int64_t)(brow + row) * IN_DIM + kbase + k;
            const int* gb = w32 + (int64_t)(bcol + row) * IN_DIM + kbase + k;
            uint32_t pa[4], pb[4];
#pragma unroll
            for (int v = 0; v < 4; ++v) {
                int32x4 ta = reinterpret_cast<const int32x4*>(ga)[v];
                int32x4 tb = reinterpret_cast<const int32x4*>(gb)[v];
                pa[v] = (uint32_t)(ta[0] & 0xff) | ((uint32_t)(ta[1] & 0xff) << 8) |
                        ((uint32_t)(ta[2] & 0xff) << 16) | ((uint32_t)(ta[3] & 0xff) << 24);
                pb[v] = (uint32_t)(tb[0] & 0xff) | ((uint32_t)(tb[1] & 0xff) << 8) |
                        ((uint32_t)(tb[2] & 0xff) << 16) | ((uint32_t)(tb[3] & 0xff) << 24);
            }
            const int sc = ((k >> 4) ^ (row & 7)) << 4;
            *reinterpret_cast<int32x4*>(lA + row * FBK + sc) = *reinterpret_cast<int32x4*>(pa);
            *reinterpret_cast<int32x4*>(lB + row * FBK + sc) = *reinterpret_cast<int32x4*>(pb);
        }
        __syncthreads();
#pragma unroll
        for (int ks = 0; ks < 2; ++ks) {
            const int gg = lane >> 4, rr = lane & 15;
            const int lc = ks * 4 + gg;
            int32x4 af[4], bf[4];
#pragma unroll
            for (int m = 0; m < 4; ++m) {
                const int row = wr * 64 + m * 16 + rr;
                af[m] = *reinterpret_cast<const int32x4*>(lA + row * FBK + ((lc ^ (row & 7)) << 4));
            }
#pragma unroll
            for (int n = 0; n < 4; ++n) {
                const int row = wc * 64 + n * 16 + rr;
                bf[n] = *reinterpret_cast<const int32x4*>(lB + row * FBK + ((lc ^ (row & 7)) << 4));
            }
#pragma unroll
            for (int m = 0; m < 4; ++m)
#pragma unroll
                for (int n = 0; n < 4; ++n)
                    acc[m][n] = __builtin_amdgcn_mfma_i32_16x16x64_i8(af[m], bf[n], acc[m][n], 0, 0, 0);
        }
        __syncthreads();
    }
    const int r4 = (lane >> 4) * 4;
    const int cl = lane & 15;
#pragma unroll
    for (int n = 0; n < 4; ++n) {
        const int col = bcol + wc * 64 + n * 16 + cl;
        const float bterm = (float)bias[col] * beta;
#pragma unroll
        for (int m = 0; m < 4; ++m) {
            const int row0 = brow + wr * 64 + m * 16 + r4;
#pragma unroll
            for (int j = 0; j < 4; ++j) {
                float y = (float)acc[m][n][j] * alpha + bterm;
                y = rintf(y);
                y = fminf(fmaxf(y, -128.0f), 127.0f);
                out[(int64_t)(row0 + j) * OUT_DIM + col] = (int)y;
            }
        }
    }
}

// ===========================================================================
extern "C" void kernel_launch(void* const* d_in, const int* in_sizes, int n_in,
                              void* d_out, int out_size, void* d_ws, size_t ws_size,
                              hipStream_t stream) {
    const int*   x     = (const int*)d_in[0];
    const int*   w     = (const int*)d_in[1];
    const int*   bias  = (const int*)d_in[2];
    const float* alpha = (const float*)d_in[3];
    const float* beta  = (const float*)d_in[4];
    int*         out   = (int*)d_out;

    const size_t need = (size_t)T_DIM * IN_DIM + (size_t)OUT_DIM * IN_DIM;

    if (ws_size >= need) {
        int8_t* x8 = (int8_t*)d_ws;
        int8_t* w8 = x8 + (size_t)T_DIM * IN_DIM;
        {
            int64_t nch = (int64_t)T_DIM * (IN_DIM / 16);
            pack_swz<<<(int)((nch + 255) / 256), 256, 0, stream>>>(x, x8, T_DIM, IN_DIM);
        }
        {
            int64_t nch = (int64_t)OUT_DIM * (IN_DIM / 16);
            pack_swz<<<(int)((nch + 255) / 256), 256, 0, stream>>>(w, w8, OUT_DIM, IN_DIM);
        }
        const int grid = (T_DIM / BM) * (OUT_DIM / BN);  // 1024
        gemm_i8_8p<<<grid, 512, 0, stream>>>(x8, w8, bias, alpha, beta, out);
    } else {
        const int grid = (T_DIM / 128) * (OUT_DIM / 128);  // 4096
        gemm_i8_fb<<<grid, 256, 0, stream>>>(x, w, bias, alpha, beta, out);
    }
}